// Round 1
// baseline (393.093 us; speedup 1.0000x reference)
//
#include <hip/hip_runtime.h>

#define NROIS 1024
#define BANDS 7
#define M_TOT (NROIS*BANDS)        // 7168
#define ROI_W 224
#define BAND_H 16
#define FLATD 512
#define HD 1024                     // 8 heads * 128
#define PROV 38
#define ALPHA 25
#define ADC 35
#define NAD 6

#define OFF_A     (M_TOT*PROV)               // 272384
#define OFF_AD    (OFF_A + M_TOT*ALPHA)      // 451584
#define OFF_MASK  (OFF_AD + NAD*M_TOT*ADC)   // 1956864
#define OFF_TOTAL (OFF_MASK + M_TOT)         // 1964032

// ---------------- Kernel 1: extract band -> adaptive pool -> conv -> relu -> 2x2 maxpool -> flat(M,512)
__global__ __launch_bounds__(256) void k_extract(
    const float* __restrict__ x, const int* __restrict__ rois,
    const float* __restrict__ conv_w, const float* __restrict__ conv_b,
    float* __restrict__ flat)
{
    __shared__ float sin_[3][BAND_H][ROI_W];   // 43008 B
    __shared__ float pl[3][10][18];            // pooled with zero border
    __shared__ float cw[432];
    __shared__ float cb[16];

    int blk = blockIdx.x;
    int r = blk / BANDS, b = blk - r*BANDS;
    int xx = rois[r*4+0];
    int yy = rois[r*4+1] + b*BAND_H;
    int t = threadIdx.x;

    for (int i=t;i<432;i+=256) cw[i]=conv_w[i];
    if (t<16) cb[t]=conv_b[t];
    for (int i=t;i<3*10*18;i+=256) ((float*)pl)[i]=0.f;

    for (int idx=t; idx<3*BAND_H*ROI_W; idx+=256){
        int c = idx/(BAND_H*ROI_W);
        int rem = idx - c*(BAND_H*ROI_W);
        int row = rem/ROI_W;
        int col = rem - row*ROI_W;
        sin_[c][row][col] = x[((size_t)(c*1024 + yy + row))*1024 + xx + col];
    }
    __syncthreads();

    // adaptive max pool (16,224) -> (8,16): 2x14 windows
    for (int idx=t; idx<384; idx+=256){
        int c = idx>>7; int rem = idx&127; int ph = rem>>4; int pw = rem&15;
        float mv = -1e30f;
        #pragma unroll
        for (int a=0;a<2;a++)
          #pragma unroll
          for (int j=0;j<14;j++)
            mv = fmaxf(mv, sin_[c][ph*2+a][pw*14+j]);
        pl[c][ph+1][pw+1] = mv;
    }
    __syncthreads();

    // conv3x3 SAME + bias + relu + 2x2 maxpool -> flat[f], f = o*32 + p*8 + q
    for (int f=t; f<512; f+=256){
        int o = f>>5; int p=(f>>3)&3; int q=f&7;
        float mx = 0.f;   // relu outputs are >= 0
        #pragma unroll
        for (int a=0;a<2;a++){
            int i = 2*p+a;
            #pragma unroll
            for (int bb=0;bb<2;bb++){
                int j = 2*q+bb;
                float s = cb[o];
                #pragma unroll
                for (int c=0;c<3;c++)
                  #pragma unroll
                  for (int kh=0;kh<3;kh++)
                    #pragma unroll
                    for (int kw=0;kw<3;kw++)
                      s += pl[c][i+kh][j+kw]*cw[((o*3+c)*3+kh)*3+kw];
                mx = fmaxf(mx, fmaxf(s, 0.f));
            }
        }
        flat[(size_t)blk*512 + f] = mx;
    }
}

// ---------------- Kernel 2: H = relu(flat @ W1cat + b1cat)   (7168x512)@(512x1024)
// B[d][n] = w1[(n>>7)*512 + d][n&127]; b1cat[n] = b1[n]
__global__ __launch_bounds__(256) void k_fc1(
    const float* __restrict__ A, const float* __restrict__ w1,
    const float* __restrict__ b1, float* __restrict__ H)
{
    __shared__ float As[16][68];
    __shared__ float Bs[16][68];
    int bm = blockIdx.x, bn = blockIdx.y;
    int t = threadIdx.x;
    int tm = t>>4, tn = t&15;
    int a_row = t>>2, a_col = (t&3)*4;
    int b_d = t>>4, b_nl = (t&15)*4;
    int khead = bn>>1;
    int colbase = (bn&1)*64;

    float acc[4][4] = {};
    const float* Ap = A + ((size_t)(bm*64 + a_row))*512 + a_col;
    const float* Bp = w1 + ((size_t)(khead*512 + b_d))*128 + colbase + b_nl;

    for (int k0=0;k0<512;k0+=16){
        float4 av = *(const float4*)(Ap + k0);
        float4 bv = *(const float4*)(Bp + (size_t)k0*128);
        As[a_col+0][a_row]=av.x; As[a_col+1][a_row]=av.y;
        As[a_col+2][a_row]=av.z; As[a_col+3][a_row]=av.w;
        *(float4*)&Bs[b_d][b_nl] = bv;
        __syncthreads();
        #pragma unroll
        for (int k=0;k<16;k++){
            float4 a4 = *(const float4*)&As[k][tm*4];
            float4 b4 = *(const float4*)&Bs[k][tn*4];
            float ar[4] = {a4.x,a4.y,a4.z,a4.w};
            float br[4] = {b4.x,b4.y,b4.z,b4.w};
            #pragma unroll
            for (int i=0;i<4;i++)
              #pragma unroll
              for (int j=0;j<4;j++)
                acc[i][j] += ar[i]*br[j];
        }
        __syncthreads();
    }
    int n0 = bn*64 + tn*4;
    float4 bias = *(const float4*)&b1[n0];
    float bb[4] = {bias.x,bias.y,bias.z,bias.w};
    #pragma unroll
    for (int i=0;i<4;i++){
        int m = bm*64 + tm*4 + i;
        float4 o;
        o.x = fmaxf(acc[i][0]+bb[0], 0.f);
        o.y = fmaxf(acc[i][1]+bb[1], 0.f);
        o.z = fmaxf(acc[i][2]+bb[2], 0.f);
        o.w = fmaxf(acc[i][3]+bb[3], 0.f);
        *(float4*)&H[(size_t)m*HD + n0] = o;
    }
}

// ---------------- Kernel 3: heads + CE losses + mask + total
__global__ __launch_bounds__(320) void k_heads(
    const float* __restrict__ H, const int* __restrict__ det_t, const int* __restrict__ cls_t,
    const float* __restrict__ w2p, const float* __restrict__ b2p,
    const float* __restrict__ w2a, const float* __restrict__ b2a,
    const float* __restrict__ w2ad, const float* __restrict__ b2ad,
    float* __restrict__ out)
{
    __shared__ float hs[HD];
    __shared__ float lg[273];
    __shared__ float lse[8];
    int m = blockIdx.x; int r = m/7;
    int t = threadIdx.x;
    for (int i=t;i<HD;i+=320) hs[i]=H[(size_t)m*HD+i];
    __syncthreads();

    if (t<273){
        float s;
        if (t<38){
            s = b2p[t];
            #pragma unroll 8
            for (int d=0;d<128;d++) s += hs[d]*w2p[d*38+t];
            out[(size_t)m*38+t] = s;
        } else if (t<63){
            int n=t-38;
            s = b2a[n];
            #pragma unroll 8
            for (int d=0;d<128;d++) s += hs[128+d]*w2a[d*25+n];
            out[OFF_A + (size_t)m*25+n] = s;
        } else {
            int l=t-63; int j=l/35; int n=l-35*j;
            s = b2ad[j*35+n];
            const float* hh = hs + (2+j)*128;
            const float* w = w2ad + (size_t)j*128*35 + n;
            #pragma unroll 8
            for (int d=0;d<128;d++) s += hh[d]*w[d*35];
            out[OFF_AD + ((size_t)j*M_TOT + m)*35 + n] = s;
        }
        lg[t]=s;
    }
    __syncthreads();

    if (t<8){
        int base,cnt;
        if (t==0){base=0;cnt=38;}
        else if (t==1){base=38;cnt=25;}
        else {base=63+(t-2)*35;cnt=35;}
        float mx=-1e30f;
        for (int i=0;i<cnt;i++) mx=fmaxf(mx,lg[base+i]);
        float s=0.f;
        for (int i=0;i<cnt;i++) s+=expf(lg[base+i]-mx);
        lse[t]=mx+logf(s);
    }
    __syncthreads();

    if (t==0){
        float det_loss = lse[0]-lg[det_t[r]];
        bool mk = det_loss < 0.25f;
        out[OFF_MASK+m] = mk?1.f:0.f;
        const int* ct = cls_t + r*8;
        float cls = (lse[0]-lg[ct[0]]) + (lse[1]-lg[38+ct[1]]);
        #pragma unroll
        for (int j=0;j<6;j++) cls += lse[2+j]-lg[63+j*35+ct[2+j]];
        if (mk) atomicAdd(out+OFF_TOTAL, cls);
    }
}

extern "C" void kernel_launch(void* const* d_in, const int* in_sizes, int n_in,
                              void* d_out, int out_size, void* d_ws, size_t ws_size,
                              hipStream_t stream) {
    const float* x      = (const float*)d_in[0];
    const int*   rois   = (const int*)d_in[1];
    const int*   det    = (const int*)d_in[2];
    const int*   cls    = (const int*)d_in[3];
    const float* conv_w = (const float*)d_in[4];
    const float* conv_b = (const float*)d_in[5];
    const float* w1     = (const float*)d_in[6];
    const float* b1     = (const float*)d_in[7];
    const float* w2p    = (const float*)d_in[8];
    const float* b2p    = (const float*)d_in[9];
    const float* w2a    = (const float*)d_in[10];
    const float* b2a    = (const float*)d_in[11];
    const float* w2ad   = (const float*)d_in[12];
    const float* b2ad   = (const float*)d_in[13];
    float* out = (float*)d_out;

    float* flat = (float*)d_ws;                       // M_TOT*512 f32
    float* H    = flat + (size_t)M_TOT*FLATD;         // M_TOT*1024 f32

    k_extract<<<M_TOT, 256, 0, stream>>>(x, rois, conv_w, conv_b, flat);
    k_fc1<<<dim3(112,16), 256, 0, stream>>>(flat, w1, b1, H);
    hipMemsetAsync(out + OFF_TOTAL, 0, sizeof(float), stream);
    k_heads<<<M_TOT, 320, 0, stream>>>(H, det, cls, w2p, b2p, w2a, b2a, w2ad, b2ad, out);
}

// Round 2
// 253.062 us; speedup vs baseline: 1.5533x; 1.5533x over previous
//
#include <hip/hip_runtime.h>

#define NROIS 1024
#define BANDS 7
#define M_TOT (NROIS*BANDS)        // 7168
#define ROI_W 224
#define BAND_H 16
#define FLATD 512
#define HD 1024                     // 8 heads * 128
#define PROV 38
#define ALPHA 25
#define ADC 35
#define NAD 6

#define OFF_A     (M_TOT*PROV)               // 272384
#define OFF_AD    (OFF_A + M_TOT*ALPHA)      // 451584
#define OFF_MASK  (OFF_AD + NAD*M_TOT*ADC)   // 1956864
#define OFF_TOTAL (OFF_MASK + M_TOT)         // 1964032

typedef __attribute__((ext_vector_type(4))) float f32x4;
typedef __attribute__((ext_vector_type(8))) short bf16x8;

static __device__ __forceinline__ unsigned short f2bf(float f){
    union { float f; unsigned int u; } v; v.f = f;
    unsigned int u = v.u;
    unsigned int r = (u + 0x7fffu + ((u >> 16) & 1u)) >> 16;
    return (unsigned short)r;
}

// ---------------- Kernel 1: extract band -> adaptive pool -> conv -> relu -> 2x2 maxpool -> flat(M,512) bf16
__global__ __launch_bounds__(256) void k_extract(
    const float* __restrict__ x, const int* __restrict__ rois,
    const float* __restrict__ conv_w, const float* __restrict__ conv_b,
    unsigned short* __restrict__ flat)
{
    __shared__ float sin_[3][BAND_H][ROI_W];   // 43008 B
    __shared__ float pl[3][10][18];            // pooled with zero border
    __shared__ float cw[432];
    __shared__ float cb[16];

    int blk = blockIdx.x;
    int r = blk / BANDS, b = blk - r*BANDS;
    int xx = rois[r*4+0];
    int yy = rois[r*4+1] + b*BAND_H;
    int t = threadIdx.x;

    for (int i=t;i<432;i+=256) cw[i]=conv_w[i];
    if (t<16) cb[t]=conv_b[t];
    for (int i=t;i<3*10*18;i+=256) ((float*)pl)[i]=0.f;

    for (int idx=t; idx<3*BAND_H*ROI_W; idx+=256){
        int c = idx/(BAND_H*ROI_W);
        int rem = idx - c*(BAND_H*ROI_W);
        int row = rem/ROI_W;
        int col = rem - row*ROI_W;
        sin_[c][row][col] = x[((size_t)(c*1024 + yy + row))*1024 + xx + col];
    }
    __syncthreads();

    for (int idx=t; idx<384; idx+=256){
        int c = idx>>7; int rem = idx&127; int ph = rem>>4; int pw = rem&15;
        float mv = -1e30f;
        #pragma unroll
        for (int a=0;a<2;a++)
          #pragma unroll
          for (int j=0;j<14;j++)
            mv = fmaxf(mv, sin_[c][ph*2+a][pw*14+j]);
        pl[c][ph+1][pw+1] = mv;
    }
    __syncthreads();

    for (int f=t; f<512; f+=256){
        int o = f>>5; int p=(f>>3)&3; int q=f&7;
        float mx = 0.f;
        #pragma unroll
        for (int a=0;a<2;a++){
            int i = 2*p+a;
            #pragma unroll
            for (int bb=0;bb<2;bb++){
                int j = 2*q+bb;
                float s = cb[o];
                #pragma unroll
                for (int c=0;c<3;c++)
                  #pragma unroll
                  for (int kh=0;kh<3;kh++)
                    #pragma unroll
                    for (int kw=0;kw<3;kw++)
                      s += pl[c][i+kh][j+kw]*cw[((o*3+c)*3+kh)*3+kw];
                mx = fmaxf(mx, fmaxf(s, 0.f));
            }
        }
        flat[(size_t)blk*512 + f] = f2bf(mx);
    }
}

// ---------------- Kernel 1b: w1 (8,512,128) f32 -> Bt[n][k] bf16 (1024x512)
__global__ __launch_bounds__(256) void k_cvt_w1(
    const float* __restrict__ w1, unsigned short* __restrict__ Bt)
{
    int i = blockIdx.x*256 + threadIdx.x;   // i = k*1024 + n
    int k = i >> 10, n = i & 1023;
    float v = w1[((size_t)(n>>7)*512 + k)*128 + (n&127)];
    Bt[(size_t)n*512 + k] = f2bf(v);
}

// ---------------- Kernel 2: H = relu(flat @ W1cat + b1cat) via bf16 MFMA
// A: [7168][512] bf16, Bt: [1024][512] bf16 (n-major, k-contig)
__global__ __launch_bounds__(256) void k_fc1_mfma(
    const unsigned short* __restrict__ A, const unsigned short* __restrict__ Bt,
    const float* __restrict__ b1, float* __restrict__ H)
{
    __shared__ short As[128][40];   // padded: row stride 80B (16B-aligned)
    __shared__ short Bs[128][40];
    int bm = blockIdx.x, bn = blockIdx.y;
    int t = threadIdx.x;
    int wid = t >> 6, lane = t & 63;
    int wr = wid >> 1, wc = wid & 1;
    int l15 = lane & 15, l4 = lane >> 4;

    f32x4 acc[4][4];
    #pragma unroll
    for (int i=0;i<4;i++)
      #pragma unroll
      for (int j=0;j<4;j++) acc[i][j] = (f32x4){0.f,0.f,0.f,0.f};

    // staging: chunk c in [0,512): row=c>>2, kc=(c&3)*8 ; each thread does c=t and c=t+256
    int r0 = t >> 2, kc0 = (t & 3) * 8;
    const unsigned short* Ap0 = A + ((size_t)(bm*128 + r0))*512 + kc0;
    const unsigned short* Ap1 = A + ((size_t)(bm*128 + 64 + r0))*512 + kc0;
    const unsigned short* Bp0 = Bt + ((size_t)(bn*128 + r0))*512 + kc0;
    const unsigned short* Bp1 = Bt + ((size_t)(bn*128 + 64 + r0))*512 + kc0;

    for (int k0 = 0; k0 < 512; k0 += 32){
        bf16x8 a0 = *(const bf16x8*)(Ap0 + k0);
        bf16x8 a1 = *(const bf16x8*)(Ap1 + k0);
        bf16x8 b0 = *(const bf16x8*)(Bp0 + k0);
        bf16x8 b1v = *(const bf16x8*)(Bp1 + k0);
        __syncthreads();
        *(bf16x8*)&As[r0][kc0]      = a0;
        *(bf16x8*)&As[64+r0][kc0]   = a1;
        *(bf16x8*)&Bs[r0][kc0]      = b0;
        *(bf16x8*)&Bs[64+r0][kc0]   = b1v;
        __syncthreads();
        bf16x8 af[4], bfr[4];
        #pragma unroll
        for (int mf=0;mf<4;mf++) af[mf]  = *(const bf16x8*)&As[wr*64 + mf*16 + l15][l4*8];
        #pragma unroll
        for (int nf=0;nf<4;nf++) bfr[nf] = *(const bf16x8*)&Bs[wc*64 + nf*16 + l15][l4*8];
        #pragma unroll
        for (int mf=0;mf<4;mf++)
          #pragma unroll
          for (int nf=0;nf<4;nf++)
            acc[mf][nf] = __builtin_amdgcn_mfma_f32_16x16x32_bf16(af[mf], bfr[nf], acc[mf][nf], 0, 0, 0);
    }

    #pragma unroll
    for (int nf=0;nf<4;nf++){
        int col = bn*128 + wc*64 + nf*16 + l15;
        float bias = b1[col];
        #pragma unroll
        for (int mf=0;mf<4;mf++){
            #pragma unroll
            for (int reg=0;reg<4;reg++){
                int row = bm*128 + wr*64 + mf*16 + l4*4 + reg;
                H[(size_t)row*HD + col] = fmaxf(acc[mf][nf][reg] + bias, 0.f);
            }
        }
    }
}

// ---------------- Kernel 3: heads GEMM + per-row LSE (grid: m-tiles x 8 heads)
__global__ __launch_bounds__(256) void k_heads(
    const float* __restrict__ H,
    const float* __restrict__ w2p, const float* __restrict__ b2p,
    const float* __restrict__ w2a, const float* __restrict__ b2a,
    const float* __restrict__ w2ad, const float* __restrict__ b2ad,
    float* __restrict__ out, float* __restrict__ lse_ws)
{
    __shared__ float Hs[32][129];
    __shared__ float Ws[128*38];
    __shared__ float bs[38];
    __shared__ float lg[32][33];

    int h = blockIdx.y;
    int m0 = blockIdx.x * 32;
    int t = threadIdx.x;

    int N; const float* W; const float* B;
    if (h == 0){ N = 38; W = w2p; B = b2p; }
    else if (h == 1){ N = 25; W = w2a; B = b2a; }
    else { N = 35; W = w2ad + (size_t)(h-2)*128*35; B = b2ad + (h-2)*35; }

    for (int i=t;i<128*N;i+=256) Ws[i] = W[i];
    if (t < N) bs[t] = B[t];
    for (int i=t;i<32*128;i+=256){
        int r = i >> 7, k = i & 127;
        Hs[r][k] = H[(size_t)(m0 + r)*HD + h*128 + k];
    }
    __syncthreads();

    for (int idx=t; idx<32*N; idx+=256){
        int col = idx >> 5, row = idx & 31;
        float s = bs[col];
        #pragma unroll 8
        for (int k=0;k<128;k++) s += Hs[row][k]*Ws[k*N + col];
        lg[row][col] = s;
        int m = m0 + row;
        if (h == 0)      out[(size_t)m*38 + col] = s;
        else if (h == 1) out[OFF_A + (size_t)m*25 + col] = s;
        else             out[OFF_AD + ((size_t)(h-2)*M_TOT + m)*35 + col] = s;
    }
    __syncthreads();

    if (t < 32){
        float mx = -1e30f;
        for (int i=0;i<N;i++) mx = fmaxf(mx, lg[t][i]);
        float s = 0.f;
        for (int i=0;i<N;i++) s += expf(lg[t][i] - mx);
        lse_ws[(size_t)(m0 + t)*8 + h] = mx + logf(s);
    }
}

// ---------------- Kernel 4: per-row losses + mask + total
__global__ __launch_bounds__(256) void k_loss(
    const float* __restrict__ lse_ws, const int* __restrict__ det_t,
    const int* __restrict__ cls_t, float* __restrict__ out)
{
    int m = blockIdx.x*256 + threadIdx.x;
    if (m >= M_TOT) return;
    int r = m / 7;
    const float* L = lse_ws + (size_t)m*8;
    float det_loss = L[0] - out[(size_t)m*38 + det_t[r]];
    bool mk = det_loss < 0.25f;
    out[OFF_MASK + m] = mk ? 1.f : 0.f;
    const int* ct = cls_t + r*8;
    float c = (L[0] - out[(size_t)m*38 + ct[0]]) + (L[1] - out[OFF_A + (size_t)m*25 + ct[1]]);
    #pragma unroll
    for (int j=0;j<6;j++)
        c += L[2+j] - out[OFF_AD + ((size_t)j*M_TOT + m)*35 + ct[2+j]];
    if (mk) atomicAdd(out + OFF_TOTAL, c);
}

extern "C" void kernel_launch(void* const* d_in, const int* in_sizes, int n_in,
                              void* d_out, int out_size, void* d_ws, size_t ws_size,
                              hipStream_t stream) {
    const float* x      = (const float*)d_in[0];
    const int*   rois   = (const int*)d_in[1];
    const int*   det    = (const int*)d_in[2];
    const int*   cls    = (const int*)d_in[3];
    const float* conv_w = (const float*)d_in[4];
    const float* conv_b = (const float*)d_in[5];
    const float* w1     = (const float*)d_in[6];
    const float* b1     = (const float*)d_in[7];
    const float* w2p    = (const float*)d_in[8];
    const float* b2p    = (const float*)d_in[9];
    const float* w2a    = (const float*)d_in[10];
    const float* b2a    = (const float*)d_in[11];
    const float* w2ad   = (const float*)d_in[12];
    const float* b2ad   = (const float*)d_in[13];
    float* out = (float*)d_out;

    char* w = (char*)d_ws;
    unsigned short* flatbf = (unsigned short*)w;                               // 7,340,032 B
    unsigned short* BtW    = (unsigned short*)(w + 7340032);                   // 1,048,576 B
    float*  H              = (float*)(w + 7340032 + 1048576);                  // 29,360,128 B
    float*  lse            = (float*)(w + 7340032 + 1048576 + 29360128);       // 229,376 B

    k_extract<<<M_TOT, 256, 0, stream>>>(x, rois, conv_w, conv_b, flatbf);
    k_cvt_w1<<<2048, 256, 0, stream>>>(w1, BtW);
    k_fc1_mfma<<<dim3(56, 8), 256, 0, stream>>>(flatbf, BtW, b1, H);
    hipMemsetAsync(out + OFF_TOTAL, 0, sizeof(float), stream);
    k_heads<<<dim3(224, 8), 256, 0, stream>>>(H, w2p, b2p, w2a, b2a, w2ad, b2ad, out, lse);
    k_loss<<<28, 256, 0, stream>>>(lse, det, cls, out);
}

// Round 3
// 202.154 us; speedup vs baseline: 1.9445x; 1.2518x over previous
//
#include <hip/hip_runtime.h>

#define NROIS 1024
#define BANDS 7
#define M_TOT (NROIS*BANDS)        // 7168
#define ROI_W 224
#define BAND_H 16
#define FLATD 512
#define HD 1024                     // 8 heads * 128
#define PROV 38
#define ALPHA 25
#define ADC 35
#define NAD 6

#define OFF_A     (M_TOT*PROV)               // 272384
#define OFF_AD    (OFF_A + M_TOT*ALPHA)      // 451584
#define OFF_MASK  (OFF_AD + NAD*M_TOT*ADC)   // 1956864
#define OFF_TOTAL (OFF_MASK + M_TOT)         // 1964032

typedef __attribute__((ext_vector_type(4))) float f32x4;
typedef __attribute__((ext_vector_type(8))) short bf16x8;

static __device__ __forceinline__ unsigned short f2bf(float f){
    union { float f; unsigned int u; } v; v.f = f;
    unsigned int u = v.u;
    unsigned int r = (u + 0x7fffu + ((u >> 16) & 1u)) >> 16;
    return (unsigned short)r;
}
static __device__ __forceinline__ float bf2f(unsigned short s){
    union { unsigned int u; float f; } v; v.u = ((unsigned int)s) << 16;
    return v.f;
}

// P[c][r][j] = max over x[c][r..r+1][j..j+13];  r in [0,1023), j in [0,1011)
#define PIDX(c,r,j) (((size_t)(c)*1023 + (r))*1024 + (j))

// ---------------- Kernel 0: precompute sliding 2x14 max P
__global__ __launch_bounds__(256) void k_precompute(
    const float* __restrict__ x, float* __restrict__ P)
{
    __shared__ float v[1024];
    int blk = blockIdx.x;
    int c = blk / 1023, r = blk - c*1023;
    int t = threadIdx.x;
    const float* row0 = x + ((size_t)c*1024 + r)*1024;
    const float* row1 = row0 + 1024;
    #pragma unroll
    for (int i=0;i<4;i++){
        int j = t + i*256;
        v[j] = fmaxf(row0[j], row1[j]);
    }
    __syncthreads();
    float* Pr = P + PIDX(c, r, 0);
    #pragma unroll
    for (int i=0;i<4;i++){
        int j = t + i*256;
        if (j < 1011){
            float mv = v[j];
            #pragma unroll
            for (int d=1;d<14;d++) mv = fmaxf(mv, v[j+d]);
            Pr[j] = mv;
        }
    }
}

// ---------------- Kernel 1: gather pooled from P -> conv -> relu -> 2x2 maxpool -> flat(M,512) bf16
__global__ __launch_bounds__(256) void k_extract(
    const float* __restrict__ P, const int* __restrict__ rois,
    const float* __restrict__ conv_w, const float* __restrict__ conv_b,
    unsigned short* __restrict__ flat)
{
    __shared__ float pl[3][10][18];            // pooled with zero border
    __shared__ float cw[432];
    __shared__ float cb[16];

    int blk = blockIdx.x;
    int r = blk / BANDS, b = blk - r*BANDS;
    int xx = rois[r*4+0];
    int yy = rois[r*4+1] + b*BAND_H;
    int t = threadIdx.x;

    for (int i=t;i<432;i+=256) cw[i]=conv_w[i];
    if (t<16) cb[t]=conv_b[t];
    for (int i=t;i<3*10*18;i+=256) ((float*)pl)[i]=0.f;
    __syncthreads();

    for (int idx=t; idx<384; idx+=256){
        int c = idx>>7; int rem = idx&127; int ph = rem>>4; int pw = rem&15;
        pl[c][ph+1][pw+1] = P[PIDX(c, yy + 2*ph, xx + 14*pw)];
    }
    __syncthreads();

    for (int f=t; f<512; f+=256){
        int o = f>>5; int p=(f>>3)&3; int q=f&7;
        float mx = 0.f;
        #pragma unroll
        for (int a=0;a<2;a++){
            int i = 2*p+a;
            #pragma unroll
            for (int bb=0;bb<2;bb++){
                int j = 2*q+bb;
                float s = cb[o];
                #pragma unroll
                for (int c=0;c<3;c++)
                  #pragma unroll
                  for (int kh=0;kh<3;kh++)
                    #pragma unroll
                    for (int kw=0;kw<3;kw++)
                      s += pl[c][i+kh][j+kw]*cw[((o*3+c)*3+kh)*3+kw];
                mx = fmaxf(mx, fmaxf(s, 0.f));
            }
        }
        flat[(size_t)blk*512 + f] = f2bf(mx);
    }
}

// ---------------- Kernel 1b: w1 (8,512,128) f32 -> Bt[n][k] bf16 (1024x512)
__global__ __launch_bounds__(256) void k_cvt_w1(
    const float* __restrict__ w1, unsigned short* __restrict__ Bt)
{
    int i = blockIdx.x*256 + threadIdx.x;   // i = k*1024 + n
    int k = i >> 10, n = i & 1023;
    float v = w1[((size_t)(n>>7)*512 + k)*128 + (n&127)];
    Bt[(size_t)n*512 + k] = f2bf(v);
}

// ---------------- Kernel 2: H = relu(flat @ W1cat + b1cat) via bf16 MFMA, H stored bf16
__global__ __launch_bounds__(256) void k_fc1_mfma(
    const unsigned short* __restrict__ A, const unsigned short* __restrict__ Bt,
    const float* __restrict__ b1, unsigned short* __restrict__ H)
{
    __shared__ short As[128][40];
    __shared__ short Bs[128][40];
    int bm = blockIdx.x, bn = blockIdx.y;
    int t = threadIdx.x;
    int wid = t >> 6, lane = t & 63;
    int wr = wid >> 1, wc = wid & 1;
    int l15 = lane & 15, l4 = lane >> 4;

    f32x4 acc[4][4];
    #pragma unroll
    for (int i=0;i<4;i++)
      #pragma unroll
      for (int j=0;j<4;j++) acc[i][j] = (f32x4){0.f,0.f,0.f,0.f};

    int r0 = t >> 2, kc0 = (t & 3) * 8;
    const unsigned short* Ap0 = A + ((size_t)(bm*128 + r0))*512 + kc0;
    const unsigned short* Ap1 = A + ((size_t)(bm*128 + 64 + r0))*512 + kc0;
    const unsigned short* Bp0 = Bt + ((size_t)(bn*128 + r0))*512 + kc0;
    const unsigned short* Bp1 = Bt + ((size_t)(bn*128 + 64 + r0))*512 + kc0;

    for (int k0 = 0; k0 < 512; k0 += 32){
        bf16x8 a0 = *(const bf16x8*)(Ap0 + k0);
        bf16x8 a1 = *(const bf16x8*)(Ap1 + k0);
        bf16x8 b0 = *(const bf16x8*)(Bp0 + k0);
        bf16x8 b1v = *(const bf16x8*)(Bp1 + k0);
        __syncthreads();
        *(bf16x8*)&As[r0][kc0]      = a0;
        *(bf16x8*)&As[64+r0][kc0]   = a1;
        *(bf16x8*)&Bs[r0][kc0]      = b0;
        *(bf16x8*)&Bs[64+r0][kc0]   = b1v;
        __syncthreads();
        bf16x8 af[4], bfr[4];
        #pragma unroll
        for (int mf=0;mf<4;mf++) af[mf]  = *(const bf16x8*)&As[wr*64 + mf*16 + l15][l4*8];
        #pragma unroll
        for (int nf=0;nf<4;nf++) bfr[nf] = *(const bf16x8*)&Bs[wc*64 + nf*16 + l15][l4*8];
        #pragma unroll
        for (int mf=0;mf<4;mf++)
          #pragma unroll
          for (int nf=0;nf<4;nf++)
            acc[mf][nf] = __builtin_amdgcn_mfma_f32_16x16x32_bf16(af[mf], bfr[nf], acc[mf][nf], 0, 0, 0);
    }

    #pragma unroll
    for (int nf=0;nf<4;nf++){
        int col = bn*128 + wc*64 + nf*16 + l15;
        float bias = b1[col];
        #pragma unroll
        for (int mf=0;mf<4;mf++){
            #pragma unroll
            for (int reg=0;reg<4;reg++){
                int row = bm*128 + wr*64 + mf*16 + l4*4 + reg;
                H[(size_t)row*HD + col] = f2bf(fmaxf(acc[mf][nf][reg] + bias, 0.f));
            }
        }
    }
}

// ---------------- Kernel 3: heads GEMM + per-row LSE (grid: m-tiles x 8 heads)
__global__ __launch_bounds__(256) void k_heads(
    const unsigned short* __restrict__ H,
    const float* __restrict__ w2p, const float* __restrict__ b2p,
    const float* __restrict__ w2a, const float* __restrict__ b2a,
    const float* __restrict__ w2ad, const float* __restrict__ b2ad,
    float* __restrict__ out, float* __restrict__ lse_ws)
{
    __shared__ float Hs[32][129];
    __shared__ float Ws[128*38];
    __shared__ float bs[38];
    __shared__ float lg[32][33];

    int h = blockIdx.y;
    int m0 = blockIdx.x * 32;
    int t = threadIdx.x;

    int N; const float* W; const float* B;
    if (h == 0){ N = 38; W = w2p; B = b2p; }
    else if (h == 1){ N = 25; W = w2a; B = b2a; }
    else { N = 35; W = w2ad + (size_t)(h-2)*128*35; B = b2ad + (h-2)*35; }

    for (int i=t;i<128*N;i+=256) Ws[i] = W[i];
    if (t < N) bs[t] = B[t];
    for (int i=t;i<32*128;i+=256){
        int r = i >> 7, k = i & 127;
        Hs[r][k] = bf2f(H[(size_t)(m0 + r)*HD + h*128 + k]);
    }
    __syncthreads();

    for (int idx=t; idx<32*N; idx+=256){
        int col = idx >> 5, row = idx & 31;
        float s = bs[col];
        #pragma unroll 8
        for (int k=0;k<128;k++) s += Hs[row][k]*Ws[k*N + col];
        lg[row][col] = s;
        int m = m0 + row;
        if (h == 0)      out[(size_t)m*38 + col] = s;
        else if (h == 1) out[OFF_A + (size_t)m*25 + col] = s;
        else             out[OFF_AD + ((size_t)(h-2)*M_TOT + m)*35 + col] = s;
    }
    __syncthreads();

    if (t < 32){
        float mx = -1e30f;
        for (int i=0;i<N;i++) mx = fmaxf(mx, lg[t][i]);
        float s = 0.f;
        for (int i=0;i<N;i++) s += expf(lg[t][i] - mx);
        lse_ws[(size_t)(m0 + t)*8 + h] = mx + logf(s);
    }
}

// ---------------- Kernel 4: per-row losses + mask + total
__global__ __launch_bounds__(256) void k_loss(
    const float* __restrict__ lse_ws, const int* __restrict__ det_t,
    const int* __restrict__ cls_t, float* __restrict__ out)
{
    int m = blockIdx.x*256 + threadIdx.x;
    if (m >= M_TOT) return;
    int r = m / 7;
    const float* L = lse_ws + (size_t)m*8;
    float det_loss = L[0] - out[(size_t)m*38 + det_t[r]];
    bool mk = det_loss < 0.25f;
    out[OFF_MASK + m] = mk ? 1.f : 0.f;
    const int* ct = cls_t + r*8;
    float c = (L[0] - out[(size_t)m*38 + ct[0]]) + (L[1] - out[OFF_A + (size_t)m*25 + ct[1]]);
    #pragma unroll
    for (int j=0;j<6;j++)
        c += L[2+j] - out[OFF_AD + ((size_t)j*M_TOT + m)*35 + ct[2+j]];
    if (mk) atomicAdd(out + OFF_TOTAL, c);
}

extern "C" void kernel_launch(void* const* d_in, const int* in_sizes, int n_in,
                              void* d_out, int out_size, void* d_ws, size_t ws_size,
                              hipStream_t stream) {
    const float* x      = (const float*)d_in[0];
    const int*   rois   = (const int*)d_in[1];
    const int*   det    = (const int*)d_in[2];
    const int*   cls    = (const int*)d_in[3];
    const float* conv_w = (const float*)d_in[4];
    const float* conv_b = (const float*)d_in[5];
    const float* w1     = (const float*)d_in[6];
    const float* b1     = (const float*)d_in[7];
    const float* w2p    = (const float*)d_in[8];
    const float* b2p    = (const float*)d_in[9];
    const float* w2a    = (const float*)d_in[10];
    const float* b2a    = (const float*)d_in[11];
    const float* w2ad   = (const float*)d_in[12];
    const float* b2ad   = (const float*)d_in[13];
    float* out = (float*)d_out;

    char* w = (char*)d_ws;
    unsigned short* flatbf = (unsigned short*)w;                    // 7,340,032 B
    unsigned short* BtW    = (unsigned short*)(w + 7340032);        // 1,048,576 B
    unsigned short* Hbf    = (unsigned short*)(w + 8388608);        // 14,680,064 B
    float*  lse            = (float*)(w + 23068672);                // 229,376 B
    float*  P              = (float*)(w + 23298048);                // 12,570,624 B

    k_precompute<<<3*1023, 256, 0, stream>>>(x, P);
    k_cvt_w1<<<2048, 256, 0, stream>>>(w1, BtW);
    k_extract<<<M_TOT, 256, 0, stream>>>(P, rois, conv_w, conv_b, flatbf);
    k_fc1_mfma<<<dim3(56, 8), 256, 0, stream>>>(flatbf, BtW, b1, Hbf);
    hipMemsetAsync(out + OFF_TOTAL, 0, sizeof(float), stream);
    k_heads<<<dim3(224, 8), 256, 0, stream>>>(Hbf, w2p, b2p, w2a, b2a, w2ad, b2ad, out, lse);
    k_loss<<<28, 256, 0, stream>>>(lse, det, cls, out);
}

// Round 4
// 176.394 us; speedup vs baseline: 2.2285x; 1.1460x over previous
//
#include <hip/hip_runtime.h>

#define NROIS 1024
#define BANDS 7
#define M_TOT (NROIS*BANDS)        // 7168
#define ROI_W 224
#define BAND_H 16
#define FLATD 512
#define HD 1024                     // 8 heads * 128
#define PROV 38
#define ALPHA 25
#define ADC 35
#define NAD 6

#define OFF_A     (M_TOT*PROV)               // 272384
#define OFF_AD    (OFF_A + M_TOT*ALPHA)      // 451584
#define OFF_MASK  (OFF_AD + NAD*M_TOT*ADC)   // 1956864
#define OFF_TOTAL (OFF_MASK + M_TOT)         // 1964032

typedef __attribute__((ext_vector_type(4))) float f32x4;
typedef __attribute__((ext_vector_type(8))) short bf16x8;

static __device__ __forceinline__ unsigned short f2bf(float f){
    union { float f; unsigned int u; } v; v.f = f;
    unsigned int u = v.u;
    unsigned int r = (u + 0x7fffu + ((u >> 16) & 1u)) >> 16;
    return (unsigned short)r;
}
static __device__ __forceinline__ float bf2f(unsigned short s){
    union { unsigned int u; float f; } v; v.u = ((unsigned int)s) << 16;
    return v.f;
}

// P[c][r][j] = max over x[c][r..r+1][j..j+13];  r in [0,1023), j in [0,1011)
#define PIDX(c,r,j) (((size_t)(c)*1023 + (r))*1024 + (j))

// ---------------- Kernel 0: precompute sliding 2x14 max P
__global__ __launch_bounds__(256) void k_precompute(
    const float* __restrict__ x, float* __restrict__ P)
{
    __shared__ float v[1024];
    int blk = blockIdx.x;
    int c = blk / 1023, r = blk - c*1023;
    int t = threadIdx.x;
    const float* row0 = x + ((size_t)c*1024 + r)*1024;
    const float* row1 = row0 + 1024;
    #pragma unroll
    for (int i=0;i<4;i++){
        int j = t + i*256;
        v[j] = fmaxf(row0[j], row1[j]);
    }
    __syncthreads();
    float* Pr = P + PIDX(c, r, 0);
    #pragma unroll
    for (int i=0;i<4;i++){
        int j = t + i*256;
        if (j < 1011){
            float mv = v[j];
            #pragma unroll
            for (int d=1;d<14;d++) mv = fmaxf(mv, v[j+d]);
            Pr[j] = mv;
        }
    }
}

// ---------------- Kernel 1: gather pooled from P -> conv -> relu -> 2x2 maxpool -> flat(M,512) bf16
__global__ __launch_bounds__(256) void k_extract(
    const float* __restrict__ P, const int* __restrict__ rois,
    const float* __restrict__ conv_w, const float* __restrict__ conv_b,
    unsigned short* __restrict__ flat)
{
    __shared__ float pl[3][10][18];
    __shared__ float cw[432];
    __shared__ float cb[16];

    int blk = blockIdx.x;
    int r = blk / BANDS, b = blk - r*BANDS;
    int xx = rois[r*4+0];
    int yy = rois[r*4+1] + b*BAND_H;
    int t = threadIdx.x;

    for (int i=t;i<432;i+=256) cw[i]=conv_w[i];
    if (t<16) cb[t]=conv_b[t];
    for (int i=t;i<3*10*18;i+=256) ((float*)pl)[i]=0.f;
    __syncthreads();

    for (int idx=t; idx<384; idx+=256){
        int c = idx>>7; int rem = idx&127; int ph = rem>>4; int pw = rem&15;
        pl[c][ph+1][pw+1] = P[PIDX(c, yy + 2*ph, xx + 14*pw)];
    }
    __syncthreads();

    for (int f=t; f<512; f+=256){
        int o = f>>5; int p=(f>>3)&3; int q=f&7;
        float mx = 0.f;
        #pragma unroll
        for (int a=0;a<2;a++){
            int i = 2*p+a;
            #pragma unroll
            for (int bb=0;bb<2;bb++){
                int j = 2*q+bb;
                float s = cb[o];
                #pragma unroll
                for (int c=0;c<3;c++)
                  #pragma unroll
                  for (int kh=0;kh<3;kh++)
                    #pragma unroll
                    for (int kw=0;kw<3;kw++)
                      s += pl[c][i+kh][j+kw]*cw[((o*3+c)*3+kh)*3+kw];
                mx = fmaxf(mx, fmaxf(s, 0.f));
            }
        }
        flat[(size_t)blk*512 + f] = f2bf(mx);
    }
}

// ---------------- Kernel 1b: w1 (8,512,128) f32 -> Bt[n][k] bf16 (1024x512)
__global__ __launch_bounds__(256) void k_cvt_w1(
    const float* __restrict__ w1, unsigned short* __restrict__ Bt)
{
    int i = blockIdx.x*256 + threadIdx.x;
    int k = i >> 10, n = i & 1023;
    float v = w1[((size_t)(n>>7)*512 + k)*128 + (n&127)];
    Bt[(size_t)n*512 + k] = f2bf(v);
}

// ---------------- Kernel 1c: head weights -> B2[8][48][128] bf16 (padded, n-major k-contig) + bias2[8][48]
__global__ __launch_bounds__(256) void k_cvt_w2(
    const float* __restrict__ w2p, const float* __restrict__ b2p,
    const float* __restrict__ w2a, const float* __restrict__ b2a,
    const float* __restrict__ w2ad, const float* __restrict__ b2ad,
    unsigned short* __restrict__ B2, float* __restrict__ bias2)
{
    int i = blockIdx.x*256 + threadIdx.x;   // < 8*48*128 = 49152
    int h = i / 6144;
    int rem = i - h*6144;
    int n = rem >> 7, k = rem & 127;
    float v = 0.f;
    if (h == 0){ if (n < 38) v = w2p[k*38 + n]; }
    else if (h == 1){ if (n < 25) v = w2a[k*25 + n]; }
    else { if (n < 35) v = w2ad[(size_t)(h-2)*128*35 + k*35 + n]; }
    B2[i] = f2bf(v);
    if (i < 8*48){
        int hh = i / 48, nn = i - hh*48;
        float bv = 0.f;
        if (hh == 0){ if (nn < 38) bv = b2p[nn]; }
        else if (hh == 1){ if (nn < 25) bv = b2a[nn]; }
        else { if (nn < 35) bv = b2ad[(hh-2)*35 + nn]; }
        bias2[i] = bv;
    }
}

// ---------------- Kernel 2: H = relu(flat @ W1cat + b1cat) via bf16 MFMA, H stored bf16
__global__ __launch_bounds__(256) void k_fc1_mfma(
    const unsigned short* __restrict__ A, const unsigned short* __restrict__ Bt,
    const float* __restrict__ b1, unsigned short* __restrict__ H)
{
    __shared__ short As[128][40];
    __shared__ short Bs[128][40];
    int bm = blockIdx.x, bn = blockIdx.y;
    int t = threadIdx.x;
    int wid = t >> 6, lane = t & 63;
    int wr = wid >> 1, wc = wid & 1;
    int l15 = lane & 15, l4 = lane >> 4;

    f32x4 acc[4][4];
    #pragma unroll
    for (int i=0;i<4;i++)
      #pragma unroll
      for (int j=0;j<4;j++) acc[i][j] = (f32x4){0.f,0.f,0.f,0.f};

    int r0 = t >> 2, kc0 = (t & 3) * 8;
    const unsigned short* Ap0 = A + ((size_t)(bm*128 + r0))*512 + kc0;
    const unsigned short* Ap1 = A + ((size_t)(bm*128 + 64 + r0))*512 + kc0;
    const unsigned short* Bp0 = Bt + ((size_t)(bn*128 + r0))*512 + kc0;
    const unsigned short* Bp1 = Bt + ((size_t)(bn*128 + 64 + r0))*512 + kc0;

    for (int k0 = 0; k0 < 512; k0 += 32){
        bf16x8 a0 = *(const bf16x8*)(Ap0 + k0);
        bf16x8 a1 = *(const bf16x8*)(Ap1 + k0);
        bf16x8 b0 = *(const bf16x8*)(Bp0 + k0);
        bf16x8 b1v = *(const bf16x8*)(Bp1 + k0);
        __syncthreads();
        *(bf16x8*)&As[r0][kc0]      = a0;
        *(bf16x8*)&As[64+r0][kc0]   = a1;
        *(bf16x8*)&Bs[r0][kc0]      = b0;
        *(bf16x8*)&Bs[64+r0][kc0]   = b1v;
        __syncthreads();
        bf16x8 af[4], bfr[4];
        #pragma unroll
        for (int mf=0;mf<4;mf++) af[mf]  = *(const bf16x8*)&As[wr*64 + mf*16 + l15][l4*8];
        #pragma unroll
        for (int nf=0;nf<4;nf++) bfr[nf] = *(const bf16x8*)&Bs[wc*64 + nf*16 + l15][l4*8];
        #pragma unroll
        for (int mf=0;mf<4;mf++)
          #pragma unroll
          for (int nf=0;nf<4;nf++)
            acc[mf][nf] = __builtin_amdgcn_mfma_f32_16x16x32_bf16(af[mf], bfr[nf], acc[mf][nf], 0, 0, 0);
    }

    #pragma unroll
    for (int nf=0;nf<4;nf++){
        int col = bn*128 + wc*64 + nf*16 + l15;
        float bias = b1[col];
        #pragma unroll
        for (int mf=0;mf<4;mf++){
            #pragma unroll
            for (int reg=0;reg<4;reg++){
                int row = bm*128 + wr*64 + mf*16 + l4*4 + reg;
                H[(size_t)row*HD + col] = f2bf(fmaxf(acc[mf][nf][reg] + bias, 0.f));
            }
        }
    }
}

// ---------------- Kernel 3: heads via bf16 MFMA. grid (28 m-tiles, 8 heads), 256 threads.
// Per block: M-tile 256 (wave w owns rows w*64..+63), N=48 padded, K=128.
__global__ __launch_bounds__(256) void k_heads_mfma(
    const unsigned short* __restrict__ H, const unsigned short* __restrict__ B2,
    const float* __restrict__ bias2, float* __restrict__ out)
{
    __shared__ short Bs[48][136];   // padded: 2-way bank alias only
    __shared__ float bsh[48];
    int h = blockIdx.y;
    int m0 = blockIdx.x * 256;
    int t = threadIdx.x;
    int wid = t >> 6, lane = t & 63;
    int l15 = lane & 15, l4 = lane >> 4;

    const unsigned short* Bh = B2 + (size_t)h*48*128;
    for (int i=t; i<768; i+=256){
        int n = i >> 4, kc = (i & 15) * 8;
        *(bf16x8*)&Bs[n][kc] = *(const bf16x8*)(Bh + n*128 + kc);
    }
    if (t < 48) bsh[t] = bias2[h*48 + t];

    f32x4 acc[4][3];
    #pragma unroll
    for (int i=0;i<4;i++)
      #pragma unroll
      for (int j=0;j<3;j++) acc[i][j] = (f32x4){0.f,0.f,0.f,0.f};
    __syncthreads();

    const unsigned short* Ap = H + ((size_t)(m0 + wid*64 + l15))*HD + h*128 + l4*8;
    #pragma unroll
    for (int ks=0; ks<4; ks++){
        int k0 = ks*32;
        bf16x8 af[4], bfr[3];
        #pragma unroll
        for (int mf=0;mf<4;mf++) af[mf] = *(const bf16x8*)(Ap + (size_t)mf*16*HD + k0);
        #pragma unroll
        for (int nf=0;nf<3;nf++) bfr[nf] = *(const bf16x8*)&Bs[nf*16 + l15][l4*8 + k0];
        #pragma unroll
        for (int mf=0;mf<4;mf++)
          #pragma unroll
          for (int nf=0;nf<3;nf++)
            acc[mf][nf] = __builtin_amdgcn_mfma_f32_16x16x32_bf16(af[mf], bfr[nf], acc[mf][nf], 0, 0, 0);
    }

    int Nh = (h==0) ? 38 : ((h==1) ? 25 : 35);
    #pragma unroll
    for (int nf=0;nf<3;nf++){
        int col = nf*16 + l15;
        if (col < Nh){
            float bias = bsh[col];
            #pragma unroll
            for (int mf=0;mf<4;mf++){
                #pragma unroll
                for (int reg=0;reg<4;reg++){
                    int m = m0 + wid*64 + mf*16 + l4*4 + reg;
                    float v = acc[mf][nf][reg] + bias;
                    size_t a;
                    if (h == 0)      a = (size_t)m*38 + col;
                    else if (h == 1) a = OFF_A + (size_t)m*25 + col;
                    else             a = OFF_AD + ((size_t)(h-2)*M_TOT + m)*35 + col;
                    out[a] = v;
                }
            }
        }
    }
}

// ---------------- Kernel 4: per-row group LSEs + losses + mask + total
__global__ __launch_bounds__(256) void k_lse_loss(
    const int* __restrict__ det_t, const int* __restrict__ cls_t,
    float* __restrict__ out)
{
    __shared__ float ls[32][8];
    __shared__ float dls[32];
    int m0 = blockIdx.x * 32;
    int t = threadIdx.x;
    int rr = t >> 3, g = t & 7;
    int m = m0 + rr;
    int r = m / 7;

    const float* p; int n;
    if (g == 0){ p = out + (size_t)m*38; n = 38; }
    else if (g == 1){ p = out + OFF_A + (size_t)m*25; n = 25; }
    else { p = out + OFF_AD + ((size_t)(g-2)*M_TOT + m)*35; n = 35; }

    float mx = -1e30f;
    for (int i=0;i<n;i++) mx = fmaxf(mx, p[i]);
    float s = 0.f;
    for (int i=0;i<n;i++) s += expf(p[i] - mx);
    float lse = mx + logf(s);

    ls[rr][g] = lse - p[cls_t[r*8 + g]];
    if (g == 0) dls[rr] = lse - p[det_t[r]];
    __syncthreads();

    if (g == 0){
        bool mk = dls[rr] < 0.25f;
        out[OFF_MASK + m] = mk ? 1.f : 0.f;
        if (mk){
            float c = 0.f;
            #pragma unroll
            for (int j=0;j<8;j++) c += ls[rr][j];
            atomicAdd(out + OFF_TOTAL, c);
        }
    }
}

extern "C" void kernel_launch(void* const* d_in, const int* in_sizes, int n_in,
                              void* d_out, int out_size, void* d_ws, size_t ws_size,
                              hipStream_t stream) {
    const float* x      = (const float*)d_in[0];
    const int*   rois   = (const int*)d_in[1];
    const int*   det    = (const int*)d_in[2];
    const int*   cls    = (const int*)d_in[3];
    const float* conv_w = (const float*)d_in[4];
    const float* conv_b = (const float*)d_in[5];
    const float* w1     = (const float*)d_in[6];
    const float* b1     = (const float*)d_in[7];
    const float* w2p    = (const float*)d_in[8];
    const float* b2p    = (const float*)d_in[9];
    const float* w2a    = (const float*)d_in[10];
    const float* b2a    = (const float*)d_in[11];
    const float* w2ad   = (const float*)d_in[12];
    const float* b2ad   = (const float*)d_in[13];
    float* out = (float*)d_out;

    char* w = (char*)d_ws;
    unsigned short* flatbf = (unsigned short*)w;                    // 7,340,032 B
    unsigned short* BtW    = (unsigned short*)(w + 7340032);        // 1,048,576 B
    unsigned short* Hbf    = (unsigned short*)(w + 8388608);        // 14,680,064 B
    unsigned short* B2     = (unsigned short*)(w + 23068672);       //    98,304 B
    float*  bias2          = (float*)(w + 23166976);                //     1,536 B
    float*  P              = (float*)(w + 23168512);                // 12,570,624 B

    k_precompute<<<3*1023, 256, 0, stream>>>(x, P);
    k_cvt_w1<<<2048, 256, 0, stream>>>(w1, BtW);
    k_cvt_w2<<<192, 256, 0, stream>>>(w2p, b2p, w2a, b2a, w2ad, b2ad, B2, bias2);
    k_extract<<<M_TOT, 256, 0, stream>>>(P, rois, conv_w, conv_b, flatbf);
    k_fc1_mfma<<<dim3(56, 8), 256, 0, stream>>>(flatbf, BtW, b1, Hbf);
    hipMemsetAsync(out + OFF_TOTAL, 0, sizeof(float), stream);
    k_heads_mfma<<<dim3(28, 8), 256, 0, stream>>>(Hbf, B2, bias2, out);
    k_lse_loss<<<224, 256, 0, stream>>>(det, cls, out);
}